// Round 2
// baseline (202.718 us; speedup 1.0000x reference)
//
#include <hip/hip_runtime.h>
#include <hip/hip_bf16.h>

// Problem constants (from reference): B=128, E=64 -> 8192 (b,e) pairs
constexpr int NB   = 32;    // neighbors
constexpr int NENV = 8;
constexpr int F0   = 16;
constexpr int F1   = 32;
constexpr int D    = 256;
constexpr int PAIRS = 128 * 64;   // 8192
constexpr float CUT = 5.0f;

__device__ __forceinline__ float fast_rcp(float x) { return __builtin_amdgcn_rcpf(x); }
__device__ __forceinline__ float silu(float a) {
  // a / (1 + e^-a); saturates correctly for large |a| (exp->inf, rcp->0)
  return a * fast_rcp(1.0f + __expf(-a));
}
__device__ __forceinline__ float fast_tanh(float t) {
  // 1 - 2/(e^{2t}+1); saturates correctly at +-1
  return 1.0f - 2.0f * fast_rcp(__expf(2.0f * t) + 1.0f);
}

// One wave (64 lanes) handles one (b,e) pair. Lane l owns channels 4l..4l+3.
__global__ __launch_bounds__(256, 2) void moon_fused(
    const float* __restrict__ r,            // [8192,3]
    const float* __restrict__ r_nb,         // [8192,32,3]
    const float* __restrict__ ee_scales,    // [8]
    const float* __restrict__ ee_kernel,    // [4,16]
    const float* __restrict__ ee_bias,      // [16]
    const float* __restrict__ beta_kernel,  // [24,32]
    const float* __restrict__ beta_bias,    // [32]
    const float* __restrict__ gamma_kernel, // [32,256]
    const float* __restrict__ dense1_kernel,// [4,256]
    const float* __restrict__ dense1_bias,  // [256]
    const float* __restrict__ out_kernel,   // [256,256]
    const float* __restrict__ out_bias,     // [256]
    float* __restrict__ out)                // [8192,256]
{
  __shared__ float s_eek[4 * F0];
  __shared__ float s_eeb[F0];
  __shared__ float s_bk[(F0 + NENV) * F1];  // 768
  __shared__ float s_bb[F1];
  __shared__ float s_is2[NENV];
  __shared__ float s_beta[4][NB * 36];      // stride 36: float4-aligned rows
  __shared__ float s_inp[4][NB * 8];        // stride 8: float4-aligned rows
  __shared__ float s_res[4][D];

  const int tid = threadIdx.x;
  const int w   = tid >> 6;    // wave id within block = pair-in-block
  const int l   = tid & 63;    // lane
  const int be  = blockIdx.x * 4 + w;

  // ---- cooperative staging of small weights (888 fp32 values) ----
  for (int i = tid; i < 888; i += 256) {
    if (i < 64)        s_eek[i]       = ee_kernel[i];
    else if (i < 80)   s_eeb[i - 64]  = ee_bias[i - 64];
    else if (i < 848)  s_bk[i - 80]   = beta_kernel[i - 80];
    else if (i < 880)  s_bb[i - 848]  = beta_bias[i - 848];
    else { float s = ee_scales[i - 880]; s_is2[i - 880] = 1.0f / (s * s); }
  }

  // ---- per-lane column registers (channels d = 4l..4l+3), coalesced float4 ----
  float gam[F1][4];
  #pragma unroll
  for (int k = 0; k < F1; ++k) {
    float4 g4 = *(const float4*)(gamma_kernel + k * D + 4 * l);
    gam[k][0] = g4.x; gam[k][1] = g4.y; gam[k][2] = g4.z; gam[k][3] = g4.w;
  }
  float d1k[4][4];
  #pragma unroll
  for (int j = 0; j < 4; ++j) {
    float4 g4 = *(const float4*)(dense1_kernel + j * D + 4 * l);
    d1k[j][0] = g4.x; d1k[j][1] = g4.y; d1k[j][2] = g4.z; d1k[j][3] = g4.w;
  }
  float d1b[4], ob[4];
  {
    float4 b4 = *(const float4*)(dense1_bias + 4 * l);
    d1b[0] = b4.x; d1b[1] = b4.y; d1b[2] = b4.z; d1b[3] = b4.w;
    float4 o4 = *(const float4*)(out_bias + 4 * l);
    ob[0] = o4.x; ob[1] = o4.y; ob[2] = o4.z; ob[3] = o4.w;
  }

  __syncthreads();

  // ---- phase 1: pairwise filter -> s_beta[w], s_inp[w] ----
  {
    const int n  = l & 31;
    const int cg = l >> 5;   // 0: beta cols 0..15 (+writes inp), 1: cols 16..31
    float rx = r[be * 3 + 0];
    float ry = r[be * 3 + 1];
    float rz = r[be * 3 + 2];
    const float* rn = r_nb + (be * NB + n) * 3;
    float dx = rn[0] - rx;
    float dy = rn[1] - ry;
    float dz = rn[2] - rz;
    float d2 = dx * dx + dy * dy + dz * dz;
    float dist = sqrtf(d2);
    float feats[4] = {dist, dx, dy, dz};
    float h[F0];
    #pragma unroll
    for (int j = 0; j < F0; ++j) {
      float t = s_eeb[j];
      #pragma unroll
      for (int i = 0; i < 4; ++i) t += feats[i] * s_eek[i * F0 + j];
      h[j] = fast_tanh(t);
    }
    float env[NENV];
    #pragma unroll
    for (int s = 0; s < NENV; ++s) env[s] = __expf(-d2 * s_is2[s]);
    float xc = dist * (1.0f / CUT);
    float fcut = (xc < 1.0f)
               ? 0.5f * (__cosf(3.14159265358979323846f * xc) + 1.0f)
               : 0.0f;
    if (cg == 0) {
      float lp = log1pf(dist);
      float inv = lp / dist;   // dist>0 for valid data (ref would NaN too)
      *(float4*)&s_inp[w][n * 8] = make_float4(lp, dx * inv, dy * inv, dz * inv);
    }
    #pragma unroll
    for (int c4 = 0; c4 < 4; ++c4) {
      float bb[4];
      #pragma unroll
      for (int cc = 0; cc < 4; ++cc) {
        int c = cg * 16 + c4 * 4 + cc;
        float a = s_bb[c];
        #pragma unroll
        for (int k = 0; k < F0; ++k) a += h[k] * s_bk[k * F1 + c];
        #pragma unroll
        for (int s = 0; s < NENV; ++s) a += env[s] * s_bk[(F0 + s) * F1 + c];
        bb[cc] = a * fcut;
      }
      *(float4*)&s_beta[w][n * 36 + cg * 16 + c4 * 4] =
          make_float4(bb[0], bb[1], bb[2], bb[3]);
    }
  }
  __syncthreads();

  // ---- phase 2: acc_d = sum_n silu(inp_n @ d1k)_d * (beta_n @ gamma)_d ----
  float acc[4] = {0.f, 0.f, 0.f, 0.f};
  for (int n = 0; n < NB; ++n) {
    const float4* bp4 = (const float4*)&s_beta[w][n * 36];  // broadcast reads
    float g[4] = {0.f, 0.f, 0.f, 0.f};
    #pragma unroll
    for (int k4 = 0; k4 < F1 / 4; ++k4) {
      float4 b4 = bp4[k4];
      #pragma unroll
      for (int c = 0; c < 4; ++c) {
        g[c] += b4.x * gam[4 * k4 + 0][c];
        g[c] += b4.y * gam[4 * k4 + 1][c];
        g[c] += b4.z * gam[4 * k4 + 2][c];
        g[c] += b4.w * gam[4 * k4 + 3][c];
      }
    }
    float4 ip = *(const float4*)&s_inp[w][n * 8];
    #pragma unroll
    for (int c = 0; c < 4; ++c) {
      float a = d1b[c] + ip.x * d1k[0][c] + ip.y * d1k[1][c]
                       + ip.z * d1k[2][c] + ip.w * d1k[3][c];
      acc[c] += silu(a) * g[c];
    }
  }
  *(float4*)&s_res[w][4 * l] = make_float4(acc[0], acc[1], acc[2], acc[3]);
  __syncthreads();

  // ---- phase 3: out = silu(res @ out_kernel + out_bias) ----
  float o[4] = {ob[0], ob[1], ob[2], ob[3]};
  #pragma unroll 4
  for (int k4 = 0; k4 < D / 4; ++k4) {
    float4 sr = *(const float4*)&s_res[w][k4 * 4];  // broadcast
    #pragma unroll
    for (int j = 0; j < 4; ++j) {
      int k = k4 * 4 + j;
      float4 w4 = *(const float4*)(out_kernel + k * D + 4 * l);  // coalesced
      float sj = (j == 0) ? sr.x : (j == 1) ? sr.y : (j == 2) ? sr.z : sr.w;
      o[0] += sj * w4.x;
      o[1] += sj * w4.y;
      o[2] += sj * w4.z;
      o[3] += sj * w4.w;
    }
  }
  float4 ro = make_float4(silu(o[0]), silu(o[1]), silu(o[2]), silu(o[3]));
  *(float4*)(out + be * D + 4 * l) = ro;
}

extern "C" void kernel_launch(void* const* d_in, const int* in_sizes, int n_in,
                              void* d_out, int out_size, void* d_ws, size_t ws_size,
                              hipStream_t stream) {
  const float* r            = (const float*)d_in[0];
  const float* r_nb         = (const float*)d_in[1];
  const float* ee_scales    = (const float*)d_in[2];
  const float* ee_kernel    = (const float*)d_in[3];
  const float* ee_bias      = (const float*)d_in[4];
  const float* beta_kernel  = (const float*)d_in[5];
  const float* beta_bias    = (const float*)d_in[6];
  const float* gamma_kernel = (const float*)d_in[7];
  const float* dense1_kernel= (const float*)d_in[8];
  const float* dense1_bias  = (const float*)d_in[9];
  const float* out_kernel   = (const float*)d_in[10];
  const float* out_bias     = (const float*)d_in[11];
  float* out = (float*)d_out;

  dim3 grid(PAIRS / 4);   // 2048 blocks, 4 waves/block, one pair per wave
  dim3 block(256);
  hipLaunchKernelGGL(moon_fused, grid, block, 0, stream,
                     r, r_nb, ee_scales, ee_kernel, ee_bias,
                     beta_kernel, beta_bias, gamma_kernel,
                     dense1_kernel, dense1_bias, out_kernel, out_bias, out);
}

// Round 3
// 191.965 us; speedup vs baseline: 1.0560x; 1.0560x over previous
//
#include <hip/hip_runtime.h>
#include <hip/hip_bf16.h>

// Problem constants (from reference): B=128, E=64 -> 8192 (b,e) pairs
constexpr int NB   = 32;    // neighbors
constexpr int NENV = 8;
constexpr int F0   = 16;
constexpr int F1   = 32;
constexpr int D    = 256;
constexpr int PAIRS = 128 * 64;   // 8192
constexpr float CUT = 5.0f;

__device__ __forceinline__ float fast_rcp(float x) { return __builtin_amdgcn_rcpf(x); }
__device__ __forceinline__ float silu(float a) {
  return a * fast_rcp(1.0f + __expf(-a));
}
__device__ __forceinline__ float fast_tanh(float t) {
  return 1.0f - 2.0f * fast_rcp(__expf(2.0f * t) + 1.0f);
}

// ---------------------------------------------------------------------------
// Kernel A: phases 1-2. One wave per (b,e) pair; lane l owns channels 4l..4l+3.
// Writes res[8192,256] (pre-out-matmul accumulator) to workspace.
// ---------------------------------------------------------------------------
__global__ __launch_bounds__(256, 2) void moon_phase12(
    const float* __restrict__ r,            // [8192,3]
    const float* __restrict__ r_nb,         // [8192,32,3]
    const float* __restrict__ ee_scales,    // [8]
    const float* __restrict__ ee_kernel,    // [4,16]
    const float* __restrict__ ee_bias,      // [16]
    const float* __restrict__ beta_kernel,  // [24,32]
    const float* __restrict__ beta_bias,    // [32]
    const float* __restrict__ gamma_kernel, // [32,256]
    const float* __restrict__ dense1_kernel,// [4,256]
    const float* __restrict__ dense1_bias,  // [256]
    float* __restrict__ resout)             // [8192,256] fp32 ws
{
  __shared__ float s_eek[4 * F0];
  __shared__ float s_eeb[F0];
  __shared__ float s_bk[(F0 + NENV) * F1];  // 768
  __shared__ float s_bb[F1];
  __shared__ float s_is2[NENV];
  __shared__ float s_beta[4][NB * 36];      // stride 36: float4-aligned rows
  __shared__ float s_inp[4][NB * 8];        // stride 8: float4-aligned rows

  const int tid = threadIdx.x;
  const int w   = tid >> 6;
  const int l   = tid & 63;
  const int be  = blockIdx.x * 4 + w;

  for (int i = tid; i < 888; i += 256) {
    if (i < 64)        s_eek[i]       = ee_kernel[i];
    else if (i < 80)   s_eeb[i - 64]  = ee_bias[i - 64];
    else if (i < 848)  s_bk[i - 80]   = beta_kernel[i - 80];
    else if (i < 880)  s_bb[i - 848]  = beta_bias[i - 848];
    else { float s = ee_scales[i - 880]; s_is2[i - 880] = 1.0f / (s * s); }
  }

  float gam[F1][4];
  #pragma unroll
  for (int k = 0; k < F1; ++k) {
    float4 g4 = *(const float4*)(gamma_kernel + k * D + 4 * l);
    gam[k][0] = g4.x; gam[k][1] = g4.y; gam[k][2] = g4.z; gam[k][3] = g4.w;
  }
  float d1k[4][4];
  #pragma unroll
  for (int j = 0; j < 4; ++j) {
    float4 g4 = *(const float4*)(dense1_kernel + j * D + 4 * l);
    d1k[j][0] = g4.x; d1k[j][1] = g4.y; d1k[j][2] = g4.z; d1k[j][3] = g4.w;
  }
  float d1b[4];
  {
    float4 b4 = *(const float4*)(dense1_bias + 4 * l);
    d1b[0] = b4.x; d1b[1] = b4.y; d1b[2] = b4.z; d1b[3] = b4.w;
  }

  __syncthreads();

  // ---- phase 1 ----
  {
    const int n  = l & 31;
    const int cg = l >> 5;
    float rx = r[be * 3 + 0];
    float ry = r[be * 3 + 1];
    float rz = r[be * 3 + 2];
    const float* rn = r_nb + (be * NB + n) * 3;
    float dx = rn[0] - rx;
    float dy = rn[1] - ry;
    float dz = rn[2] - rz;
    float d2 = dx * dx + dy * dy + dz * dz;
    float dist = sqrtf(d2);
    float feats[4] = {dist, dx, dy, dz};
    float h[F0];
    #pragma unroll
    for (int j = 0; j < F0; ++j) {
      float t = s_eeb[j];
      #pragma unroll
      for (int i = 0; i < 4; ++i) t += feats[i] * s_eek[i * F0 + j];
      h[j] = fast_tanh(t);
    }
    float env[NENV];
    #pragma unroll
    for (int s = 0; s < NENV; ++s) env[s] = __expf(-d2 * s_is2[s]);
    float xc = dist * (1.0f / CUT);
    float fcut = (xc < 1.0f)
               ? 0.5f * (__cosf(3.14159265358979323846f * xc) + 1.0f)
               : 0.0f;
    if (cg == 0) {
      float lp = log1pf(dist);
      float inv = lp / dist;
      *(float4*)&s_inp[w][n * 8] = make_float4(lp, dx * inv, dy * inv, dz * inv);
    }
    #pragma unroll
    for (int c4 = 0; c4 < 4; ++c4) {
      float bb[4];
      #pragma unroll
      for (int cc = 0; cc < 4; ++cc) {
        int c = cg * 16 + c4 * 4 + cc;
        float a = s_bb[c];
        #pragma unroll
        for (int k = 0; k < F0; ++k) a += h[k] * s_bk[k * F1 + c];
        #pragma unroll
        for (int s = 0; s < NENV; ++s) a += env[s] * s_bk[(F0 + s) * F1 + c];
        bb[cc] = a * fcut;
      }
      *(float4*)&s_beta[w][n * 36 + cg * 16 + c4 * 4] =
          make_float4(bb[0], bb[1], bb[2], bb[3]);
    }
  }
  __syncthreads();

  // ---- phase 2 ----
  float acc[4] = {0.f, 0.f, 0.f, 0.f};
  for (int n = 0; n < NB; ++n) {
    const float4* bp4 = (const float4*)&s_beta[w][n * 36];
    float g[4] = {0.f, 0.f, 0.f, 0.f};
    #pragma unroll
    for (int k4 = 0; k4 < F1 / 4; ++k4) {
      float4 b4 = bp4[k4];
      #pragma unroll
      for (int c = 0; c < 4; ++c) {
        g[c] += b4.x * gam[4 * k4 + 0][c];
        g[c] += b4.y * gam[4 * k4 + 1][c];
        g[c] += b4.z * gam[4 * k4 + 2][c];
        g[c] += b4.w * gam[4 * k4 + 3][c];
      }
    }
    float4 ip = *(const float4*)&s_inp[w][n * 8];
    #pragma unroll
    for (int c = 0; c < 4; ++c) {
      float a = d1b[c] + ip.x * d1k[0][c] + ip.y * d1k[1][c]
                       + ip.z * d1k[2][c] + ip.w * d1k[3][c];
      acc[c] += silu(a) * g[c];
    }
  }
  *(float4*)(resout + be * D + 4 * l) = make_float4(acc[0], acc[1], acc[2], acc[3]);
}

// ---------------------------------------------------------------------------
// Kernel B: out = silu(res @ W + b). 256 blocks x 32 rows; W read once per
// block (L1-shared across the 4 waves) instead of once per wave.
// Thread (g=t/64, l=t%64): rows 8g..8g+7, cols 4l..4l+3.
// ---------------------------------------------------------------------------
__global__ __launch_bounds__(256, 2) void moon_outgemm(
    const float* __restrict__ res,   // [8192,256]
    const float* __restrict__ W,     // [256,256]
    const float* __restrict__ bias,  // [256]
    float* __restrict__ out)         // [8192,256]
{
  __shared__ float s_in[32 * 256];   // 32 KB res tile

  const int t = threadIdx.x;
  const int g = t >> 6;
  const int l = t & 63;
  const int row0 = blockIdx.x * 32;

  // stage res tile: 2048 float4s over 256 threads
  {
    const float4* src = (const float4*)(res + row0 * 256);
    float4* dst = (float4*)s_in;
    #pragma unroll
    for (int i = 0; i < 8; ++i) dst[t + 256 * i] = src[t + 256 * i];
  }
  float4 b4 = *(const float4*)(bias + 4 * l);
  __syncthreads();

  float acc[8][4] = {};
  const float* Wp = W + 4 * l;
  for (int k4 = 0; k4 < 64; ++k4) {
    float4 wv[4];
    #pragma unroll
    for (int j = 0; j < 4; ++j)
      wv[j] = *(const float4*)(Wp + (k4 * 4 + j) * 256);   // coalesced, L1-shared
    #pragma unroll
    for (int rr = 0; rr < 8; ++rr) {
      float4 a4 = *(const float4*)&s_in[(g * 8 + rr) * 256 + k4 * 4];  // broadcast
      #pragma unroll
      for (int c = 0; c < 4; ++c) {
        float* av = (float*)&a4;
        acc[rr][c] += av[0] * ((float*)&wv[0])[c];
        acc[rr][c] += av[1] * ((float*)&wv[1])[c];
        acc[rr][c] += av[2] * ((float*)&wv[2])[c];
        acc[rr][c] += av[3] * ((float*)&wv[3])[c];
      }
    }
  }
  #pragma unroll
  for (int rr = 0; rr < 8; ++rr) {
    int row = row0 + g * 8 + rr;
    float4 o = make_float4(silu(acc[rr][0] + b4.x), silu(acc[rr][1] + b4.y),
                           silu(acc[rr][2] + b4.z), silu(acc[rr][3] + b4.w));
    *(float4*)(out + row * D + 4 * l) = o;
  }
}

// ---------------------------------------------------------------------------
// Fallback: fully fused single kernel (round-2 version) for tiny ws_size.
// ---------------------------------------------------------------------------
__global__ __launch_bounds__(256, 2) void moon_fused(
    const float* __restrict__ r, const float* __restrict__ r_nb,
    const float* __restrict__ ee_scales, const float* __restrict__ ee_kernel,
    const float* __restrict__ ee_bias, const float* __restrict__ beta_kernel,
    const float* __restrict__ beta_bias, const float* __restrict__ gamma_kernel,
    const float* __restrict__ dense1_kernel, const float* __restrict__ dense1_bias,
    const float* __restrict__ out_kernel, const float* __restrict__ out_bias,
    float* __restrict__ out)
{
  __shared__ float s_eek[4 * F0];
  __shared__ float s_eeb[F0];
  __shared__ float s_bk[(F0 + NENV) * F1];
  __shared__ float s_bb[F1];
  __shared__ float s_is2[NENV];
  __shared__ float s_beta[4][NB * 36];
  __shared__ float s_inp[4][NB * 8];
  __shared__ float s_res[4][D];

  const int tid = threadIdx.x;
  const int w   = tid >> 6;
  const int l   = tid & 63;
  const int be  = blockIdx.x * 4 + w;

  for (int i = tid; i < 888; i += 256) {
    if (i < 64)        s_eek[i]       = ee_kernel[i];
    else if (i < 80)   s_eeb[i - 64]  = ee_bias[i - 64];
    else if (i < 848)  s_bk[i - 80]   = beta_kernel[i - 80];
    else if (i < 880)  s_bb[i - 848]  = beta_bias[i - 848];
    else { float s = ee_scales[i - 880]; s_is2[i - 880] = 1.0f / (s * s); }
  }

  float gam[F1][4];
  #pragma unroll
  for (int k = 0; k < F1; ++k) {
    float4 g4 = *(const float4*)(gamma_kernel + k * D + 4 * l);
    gam[k][0] = g4.x; gam[k][1] = g4.y; gam[k][2] = g4.z; gam[k][3] = g4.w;
  }
  float d1k[4][4];
  #pragma unroll
  for (int j = 0; j < 4; ++j) {
    float4 g4 = *(const float4*)(dense1_kernel + j * D + 4 * l);
    d1k[j][0] = g4.x; d1k[j][1] = g4.y; d1k[j][2] = g4.z; d1k[j][3] = g4.w;
  }
  float d1b[4], ob[4];
  {
    float4 b4 = *(const float4*)(dense1_bias + 4 * l);
    d1b[0] = b4.x; d1b[1] = b4.y; d1b[2] = b4.z; d1b[3] = b4.w;
    float4 o4 = *(const float4*)(out_bias + 4 * l);
    ob[0] = o4.x; ob[1] = o4.y; ob[2] = o4.z; ob[3] = o4.w;
  }
  __syncthreads();
  {
    const int n  = l & 31;
    const int cg = l >> 5;
    float rx = r[be * 3 + 0], ry = r[be * 3 + 1], rz = r[be * 3 + 2];
    const float* rn = r_nb + (be * NB + n) * 3;
    float dx = rn[0] - rx, dy = rn[1] - ry, dz = rn[2] - rz;
    float d2 = dx * dx + dy * dy + dz * dz;
    float dist = sqrtf(d2);
    float feats[4] = {dist, dx, dy, dz};
    float h[F0];
    #pragma unroll
    for (int j = 0; j < F0; ++j) {
      float t = s_eeb[j];
      #pragma unroll
      for (int i = 0; i < 4; ++i) t += feats[i] * s_eek[i * F0 + j];
      h[j] = fast_tanh(t);
    }
    float env[NENV];
    #pragma unroll
    for (int s = 0; s < NENV; ++s) env[s] = __expf(-d2 * s_is2[s]);
    float xc = dist * (1.0f / CUT);
    float fcut = (xc < 1.0f) ? 0.5f * (__cosf(3.14159265358979323846f * xc) + 1.0f) : 0.0f;
    if (cg == 0) {
      float lp = log1pf(dist);
      float inv = lp / dist;
      *(float4*)&s_inp[w][n * 8] = make_float4(lp, dx * inv, dy * inv, dz * inv);
    }
    #pragma unroll
    for (int c4 = 0; c4 < 4; ++c4) {
      float bb[4];
      #pragma unroll
      for (int cc = 0; cc < 4; ++cc) {
        int c = cg * 16 + c4 * 4 + cc;
        float a = s_bb[c];
        #pragma unroll
        for (int k = 0; k < F0; ++k) a += h[k] * s_bk[k * F1 + c];
        #pragma unroll
        for (int s = 0; s < NENV; ++s) a += env[s] * s_bk[(F0 + s) * F1 + c];
        bb[cc] = a * fcut;
      }
      *(float4*)&s_beta[w][n * 36 + cg * 16 + c4 * 4] = make_float4(bb[0], bb[1], bb[2], bb[3]);
    }
  }
  __syncthreads();
  float acc[4] = {0.f, 0.f, 0.f, 0.f};
  for (int n = 0; n < NB; ++n) {
    const float4* bp4 = (const float4*)&s_beta[w][n * 36];
    float g[4] = {0.f, 0.f, 0.f, 0.f};
    #pragma unroll
    for (int k4 = 0; k4 < F1 / 4; ++k4) {
      float4 b4 = bp4[k4];
      #pragma unroll
      for (int c = 0; c < 4; ++c) {
        g[c] += b4.x * gam[4 * k4 + 0][c];
        g[c] += b4.y * gam[4 * k4 + 1][c];
        g[c] += b4.z * gam[4 * k4 + 2][c];
        g[c] += b4.w * gam[4 * k4 + 3][c];
      }
    }
    float4 ip = *(const float4*)&s_inp[w][n * 8];
    #pragma unroll
    for (int c = 0; c < 4; ++c) {
      float a = d1b[c] + ip.x * d1k[0][c] + ip.y * d1k[1][c]
                       + ip.z * d1k[2][c] + ip.w * d1k[3][c];
      acc[c] += silu(a) * g[c];
    }
  }
  *(float4*)&s_res[w][4 * l] = make_float4(acc[0], acc[1], acc[2], acc[3]);
  __syncthreads();
  float o[4] = {ob[0], ob[1], ob[2], ob[3]};
  #pragma unroll 4
  for (int k4 = 0; k4 < D / 4; ++k4) {
    float4 sr = *(const float4*)&s_res[w][k4 * 4];
    #pragma unroll
    for (int j = 0; j < 4; ++j) {
      int k = k4 * 4 + j;
      float4 w4 = *(const float4*)(out_kernel + k * D + 4 * l);
      float sj = (j == 0) ? sr.x : (j == 1) ? sr.y : (j == 2) ? sr.z : sr.w;
      o[0] += sj * w4.x; o[1] += sj * w4.y; o[2] += sj * w4.z; o[3] += sj * w4.w;
    }
  }
  float4 ro = make_float4(silu(o[0]), silu(o[1]), silu(o[2]), silu(o[3]));
  *(float4*)(out + be * D + 4 * l) = ro;
}

extern "C" void kernel_launch(void* const* d_in, const int* in_sizes, int n_in,
                              void* d_out, int out_size, void* d_ws, size_t ws_size,
                              hipStream_t stream) {
  const float* r            = (const float*)d_in[0];
  const float* r_nb         = (const float*)d_in[1];
  const float* ee_scales    = (const float*)d_in[2];
  const float* ee_kernel    = (const float*)d_in[3];
  const float* ee_bias      = (const float*)d_in[4];
  const float* beta_kernel  = (const float*)d_in[5];
  const float* beta_bias    = (const float*)d_in[6];
  const float* gamma_kernel = (const float*)d_in[7];
  const float* dense1_kernel= (const float*)d_in[8];
  const float* dense1_bias  = (const float*)d_in[9];
  const float* out_kernel   = (const float*)d_in[10];
  const float* out_bias     = (const float*)d_in[11];
  float* out = (float*)d_out;

  const size_t res_bytes = (size_t)PAIRS * D * sizeof(float);
  if (ws_size >= res_bytes) {
    float* res = (float*)d_ws;
    hipLaunchKernelGGL(moon_phase12, dim3(PAIRS / 4), dim3(256), 0, stream,
                       r, r_nb, ee_scales, ee_kernel, ee_bias,
                       beta_kernel, beta_bias, gamma_kernel,
                       dense1_kernel, dense1_bias, res);
    hipLaunchKernelGGL(moon_outgemm, dim3(PAIRS / 32), dim3(256), 0, stream,
                       res, out_kernel, out_bias, out);
  } else {
    hipLaunchKernelGGL(moon_fused, dim3(PAIRS / 4), dim3(256), 0, stream,
                       r, r_nb, ee_scales, ee_kernel, ee_bias,
                       beta_kernel, beta_bias, gamma_kernel,
                       dense1_kernel, dense1_bias, out_kernel, out_bias, out);
  }
}

// Round 4
// 156.735 us; speedup vs baseline: 1.2934x; 1.2248x over previous
//
#include <hip/hip_runtime.h>
#include <hip/hip_bf16.h>

constexpr int NB   = 32;
constexpr int NENV = 8;
constexpr int F0   = 16;
constexpr int F1   = 32;
constexpr int D    = 256;
constexpr int PAIRS = 128 * 64;   // 8192
constexpr float CUT = 5.0f;

typedef float f32x4 __attribute__((ext_vector_type(4)));
typedef short s16x8 __attribute__((ext_vector_type(8)));

__device__ __forceinline__ float fast_rcp(float x) { return __builtin_amdgcn_rcpf(x); }
__device__ __forceinline__ float silu(float a) {
  return a * fast_rcp(1.0f + __expf(-a));
}
__device__ __forceinline__ float fast_tanh(float t) {
  return 1.0f - 2.0f * fast_rcp(__expf(2.0f * t) + 1.0f);
}
__device__ __forceinline__ unsigned short f2bf(float f) {
  __hip_bfloat16 h = __float2bfloat16(f);
  unsigned short u; __builtin_memcpy(&u, &h, 2); return u;
}

// ---------------------------------------------------------------------------
// Kernel A (phases 1-2, MFMA gamma matmul). One wave per (b,e) pair.
// ---------------------------------------------------------------------------
__global__ __launch_bounds__(256, 2) void moon_phase12(
    const float* __restrict__ r,            // [8192,3]
    const float* __restrict__ r_nb,         // [8192,32,3]
    const float* __restrict__ ee_scales,    // [8]
    const float* __restrict__ ee_kernel,    // [4,16]
    const float* __restrict__ ee_bias,      // [16]
    const float* __restrict__ beta_kernel,  // [24,32]
    const float* __restrict__ beta_bias,    // [32]
    const float* __restrict__ gamma_kernel, // [32,256]
    const float* __restrict__ dense1_kernel,// [4,256]
    const float* __restrict__ dense1_bias,  // [256]
    float* __restrict__ resout)             // [8192,256] fp32 ws
{
  __shared__ float s_eek[4 * F0];
  __shared__ float s_eeb[F0];
  __shared__ float s_bk[(F0 + NENV) * F1];          // 768
  __shared__ float s_bb[F1];
  __shared__ float s_is2[NENV];
  __shared__ unsigned short s_ghT[D * 40];          // G^T bf16, row=d stride 40
  __shared__ float s_d1k[4 * D];
  __shared__ float s_d1b[D];
  __shared__ unsigned short s_betah[4][NB * 40];    // beta bf16, row=n stride 40
  __shared__ float s_inp[4][NB * 8];
  __shared__ float s_res[4][D];

  const int tid = threadIdx.x;
  const int w   = tid >> 6;
  const int l   = tid & 63;
  const int be  = blockIdx.x * 4 + w;

  // ---- staging: small weights ----
  for (int i = tid; i < 888; i += 256) {
    if (i < 64)        s_eek[i]       = ee_kernel[i];
    else if (i < 80)   s_eeb[i - 64]  = ee_bias[i - 64];
    else if (i < 848)  s_bk[i - 80]   = beta_kernel[i - 80];
    else if (i < 880)  s_bb[i - 848]  = beta_bias[i - 848];
    else { float s = ee_scales[i - 880]; s_is2[i - 880] = 1.0f / (s * s); }
  }
  // ---- staging: gamma -> bf16 transposed (thread t owns output row d=t) ----
  {
    const int d = tid;
    unsigned int pk[16];
    #pragma unroll
    for (int k2 = 0; k2 < 16; ++k2) {
      unsigned short lo = f2bf(gamma_kernel[(2 * k2 + 0) * D + d]);
      unsigned short hi = f2bf(gamma_kernel[(2 * k2 + 1) * D + d]);
      pk[k2] = (unsigned int)lo | ((unsigned int)hi << 16);
    }
    uint4* dst = (uint4*)&s_ghT[d * 40];
    #pragma unroll
    for (int q = 0; q < 4; ++q)
      dst[q] = make_uint4(pk[4*q], pk[4*q+1], pk[4*q+2], pk[4*q+3]);
  }
  // ---- staging: dense1 ----
  *(float4*)&s_d1k[4 * tid] = *(const float4*)(dense1_kernel + 4 * tid);
  if (tid < 64) *(float4*)&s_d1b[4 * tid] = *(const float4*)(dense1_bias + 4 * tid);

  __syncthreads();

  // ---- phase 1: pairwise filter -> s_betah[w] (bf16), s_inp[w] ----
  {
    const int n  = l & 31;
    const int cg = l >> 5;
    float rx = r[be * 3 + 0];
    float ry = r[be * 3 + 1];
    float rz = r[be * 3 + 2];
    const float* rn = r_nb + (be * NB + n) * 3;
    float dx = rn[0] - rx;
    float dy = rn[1] - ry;
    float dz = rn[2] - rz;
    float d2 = dx * dx + dy * dy + dz * dz;
    float dist = sqrtf(d2);
    float feats[4] = {dist, dx, dy, dz};
    float h[F0];
    #pragma unroll
    for (int j = 0; j < F0; ++j) {
      float t = s_eeb[j];
      #pragma unroll
      for (int i = 0; i < 4; ++i) t += feats[i] * s_eek[i * F0 + j];
      h[j] = fast_tanh(t);
    }
    float env[NENV];
    #pragma unroll
    for (int s = 0; s < NENV; ++s) env[s] = __expf(-d2 * s_is2[s]);
    float xc = dist * (1.0f / CUT);
    float fcut = (xc < 1.0f)
               ? 0.5f * (__cosf(3.14159265358979323846f * xc) + 1.0f)
               : 0.0f;
    if (cg == 0) {
      float lp = log1pf(dist);
      float inv = lp / dist;
      *(float4*)&s_inp[w][n * 8] = make_float4(lp, dx * inv, dy * inv, dz * inv);
    }
    unsigned int pk[8];
    #pragma unroll
    for (int c4 = 0; c4 < 4; ++c4) {
      float bb[4];
      #pragma unroll
      for (int cc = 0; cc < 4; ++cc) {
        int c = cg * 16 + c4 * 4 + cc;
        float a = s_bb[c];
        #pragma unroll
        for (int k = 0; k < F0; ++k) a += h[k] * s_bk[k * F1 + c];
        #pragma unroll
        for (int s = 0; s < NENV; ++s) a += env[s] * s_bk[(F0 + s) * F1 + c];
        bb[cc] = a * fcut;
      }
      pk[c4 * 2 + 0] = (unsigned int)f2bf(bb[0]) | ((unsigned int)f2bf(bb[1]) << 16);
      pk[c4 * 2 + 1] = (unsigned int)f2bf(bb[2]) | ((unsigned int)f2bf(bb[3]) << 16);
    }
    uint4* bdst = (uint4*)&s_betah[w][n * 40 + cg * 16];
    bdst[0] = make_uint4(pk[0], pk[1], pk[2], pk[3]);
    bdst[1] = make_uint4(pk[4], pk[5], pk[6], pk[7]);
  }
  __syncthreads();

  // ---- phase 2: MFMA gammaM = beta @ G, Hadamard with feat, reduce over n ----
  const int li = l & 15;          // d-within-tile / m-within-tile
  const int g  = l >> 4;          // k-slot group (and C row group)
  const int kst = g * 8;

  // A fragments for the two m-tiles (resident across nt loop)
  s16x8 a0 = *(const s16x8*)&s_betah[w][(0 * 16 + li) * 40 + kst];
  s16x8 a1 = *(const s16x8*)&s_betah[w][(1 * 16 + li) * 40 + kst];

  // inp rows this lane will need: nrow = mt*16 + g*4 + reg  (reused all nt)
  float4 ip[8];
  #pragma unroll
  for (int mt = 0; mt < 2; ++mt)
    #pragma unroll
    for (int reg = 0; reg < 4; ++reg)
      ip[mt * 4 + reg] = *(const float4*)&s_inp[w][(mt * 16 + g * 4 + reg) * 8];

  float rpart[16];
  #pragma unroll
  for (int nt = 0; nt < 16; ++nt) {
    const int d = nt * 16 + li;
    s16x8 b = *(const s16x8*)&s_ghT[d * 40 + kst];
    f32x4 z = {0.f, 0.f, 0.f, 0.f};
    f32x4 c0 = __builtin_amdgcn_mfma_f32_16x16x32_bf16(a0, b, z, 0, 0, 0);
    f32x4 c1 = __builtin_amdgcn_mfma_f32_16x16x32_bf16(a1, b, z, 0, 0, 0);
    float w0 = s_d1k[0 * D + d];
    float w1 = s_d1k[1 * D + d];
    float w2 = s_d1k[2 * D + d];
    float w3 = s_d1k[3 * D + d];
    float bia = s_d1b[d];
    float p = 0.f;
    #pragma unroll
    for (int reg = 0; reg < 4; ++reg) {
      float4 i0 = ip[reg];
      float aa0 = bia + i0.x * w0 + i0.y * w1 + i0.z * w2 + i0.w * w3;
      p += silu(aa0) * c0[reg];
      float4 i1 = ip[4 + reg];
      float aa1 = bia + i1.x * w0 + i1.y * w1 + i1.z * w2 + i1.w * w3;
      p += silu(aa1) * c1[reg];
    }
    rpart[nt] = p;
  }
  // sum over the 4 row-groups (lanes differing in bits 4..5)
  #pragma unroll
  for (int nt = 0; nt < 16; ++nt) {
    float v = rpart[nt];
    v += __shfl_xor(v, 16);
    v += __shfl_xor(v, 32);
    rpart[nt] = v;
  }
  // transpose via per-wave LDS region (writer: group g == nt&3), then coalesced store
  #pragma unroll
  for (int nt = 0; nt < 16; ++nt) {
    if (g == (nt & 3)) s_res[w][nt * 16 + li] = rpart[nt];
  }
  // wave-local LDS RAW: LDS pipe is in-order per wave; compiler inserts lgkmcnt
  float4 rv = *(const float4*)&s_res[w][4 * l];
  *(float4*)(resout + be * D + 4 * l) = rv;
}

// ---------------------------------------------------------------------------
// Kernel B: out = silu(res @ W + b). 256 blocks x 32 rows (unchanged).
// ---------------------------------------------------------------------------
__global__ __launch_bounds__(256, 2) void moon_outgemm(
    const float* __restrict__ res,   // [8192,256]
    const float* __restrict__ W,     // [256,256]
    const float* __restrict__ bias,  // [256]
    float* __restrict__ out)         // [8192,256]
{
  __shared__ float s_in[32 * 256];

  const int t = threadIdx.x;
  const int g = t >> 6;
  const int l = t & 63;
  const int row0 = blockIdx.x * 32;

  {
    const float4* src = (const float4*)(res + row0 * 256);
    float4* dst = (float4*)s_in;
    #pragma unroll
    for (int i = 0; i < 8; ++i) dst[t + 256 * i] = src[t + 256 * i];
  }
  float4 b4 = *(const float4*)(bias + 4 * l);
  __syncthreads();

  float acc[8][4] = {};
  const float* Wp = W + 4 * l;
  for (int k4 = 0; k4 < 64; ++k4) {
    float4 wv[4];
    #pragma unroll
    for (int j = 0; j < 4; ++j)
      wv[j] = *(const float4*)(Wp + (k4 * 4 + j) * 256);
    #pragma unroll
    for (int rr = 0; rr < 8; ++rr) {
      float4 a4 = *(const float4*)&s_in[(g * 8 + rr) * 256 + k4 * 4];
      #pragma unroll
      for (int c = 0; c < 4; ++c) {
        float* av = (float*)&a4;
        acc[rr][c] += av[0] * ((float*)&wv[0])[c];
        acc[rr][c] += av[1] * ((float*)&wv[1])[c];
        acc[rr][c] += av[2] * ((float*)&wv[2])[c];
        acc[rr][c] += av[3] * ((float*)&wv[3])[c];
      }
    }
  }
  #pragma unroll
  for (int rr = 0; rr < 8; ++rr) {
    int row = row0 + g * 8 + rr;
    float4 o = make_float4(silu(acc[rr][0] + b4.x), silu(acc[rr][1] + b4.y),
                           silu(acc[rr][2] + b4.z), silu(acc[rr][3] + b4.w));
    *(float4*)(out + row * D + 4 * l) = o;
  }
}

extern "C" void kernel_launch(void* const* d_in, const int* in_sizes, int n_in,
                              void* d_out, int out_size, void* d_ws, size_t ws_size,
                              hipStream_t stream) {
  const float* r            = (const float*)d_in[0];
  const float* r_nb         = (const float*)d_in[1];
  const float* ee_scales    = (const float*)d_in[2];
  const float* ee_kernel    = (const float*)d_in[3];
  const float* ee_bias      = (const float*)d_in[4];
  const float* beta_kernel  = (const float*)d_in[5];
  const float* beta_bias    = (const float*)d_in[6];
  const float* gamma_kernel = (const float*)d_in[7];
  const float* dense1_kernel= (const float*)d_in[8];
  const float* dense1_bias  = (const float*)d_in[9];
  const float* out_kernel   = (const float*)d_in[10];
  const float* out_bias     = (const float*)d_in[11];
  float* out = (float*)d_out;

  float* res = (float*)d_ws;   // 8 MB fp32 workspace
  hipLaunchKernelGGL(moon_phase12, dim3(PAIRS / 4), dim3(256), 0, stream,
                     r, r_nb, ee_scales, ee_kernel, ee_bias,
                     beta_kernel, beta_bias, gamma_kernel,
                     dense1_kernel, dense1_bias, res);
  hipLaunchKernelGGL(moon_outgemm, dim3(PAIRS / 32), dim3(256), 0, stream,
                     res, out_kernel, out_bias, out);
}

// Round 5
// 128.185 us; speedup vs baseline: 1.5815x; 1.2227x over previous
//
#include <hip/hip_runtime.h>
#include <hip/hip_bf16.h>

constexpr int NB   = 32;
constexpr int NENV = 8;
constexpr int F0   = 16;
constexpr int F1   = 32;
constexpr int D    = 256;
constexpr int PAIRS = 128 * 64;   // 8192
constexpr float CUT = 5.0f;
constexpr int WT_STRIDE = 264;    // ushorts per row of Wt (16B aligned, breaks 512B aliasing)

typedef float f32x4 __attribute__((ext_vector_type(4)));
typedef short s16x8 __attribute__((ext_vector_type(8)));

__device__ __forceinline__ float fast_rcp(float x) { return __builtin_amdgcn_rcpf(x); }
__device__ __forceinline__ float silu(float a) {
  return a * fast_rcp(1.0f + __expf(-a));
}
__device__ __forceinline__ float fast_tanh(float t) {
  return 1.0f - 2.0f * fast_rcp(__expf(2.0f * t) + 1.0f);
}
__device__ __forceinline__ unsigned short f2bf(float f) {
  __hip_bfloat16 h = __float2bfloat16(f);
  unsigned short u; __builtin_memcpy(&u, &h, 2); return u;
}

// ---------------------------------------------------------------------------
// Kernel A (phases 1-2, MFMA gamma matmul). One wave per (b,e) pair.
// Writes res as bf16 [8192,256] (A-frag-ready, row-major) to ws.
// Blocks 0..63 additionally transpose+convert out_kernel -> Wt bf16 in ws.
// ---------------------------------------------------------------------------
__global__ __launch_bounds__(256, 4) void moon_phase12(
    const float* __restrict__ r,            // [8192,3]
    const float* __restrict__ r_nb,         // [8192,32,3]
    const float* __restrict__ ee_scales,    // [8]
    const float* __restrict__ ee_kernel,    // [4,16]
    const float* __restrict__ ee_bias,      // [16]
    const float* __restrict__ beta_kernel,  // [24,32]
    const float* __restrict__ beta_bias,    // [32]
    const float* __restrict__ gamma_kernel, // [32,256]
    const float* __restrict__ dense1_kernel,// [4,256]
    const float* __restrict__ dense1_bias,  // [256]
    const float* __restrict__ out_kernel,   // [256,256] (for Wt conversion)
    unsigned short* __restrict__ resh,      // [8192,256] bf16 ws
    unsigned short* __restrict__ wt)        // [256, WT_STRIDE] bf16 ws (W^T)
{
  __shared__ float s_eek[4 * F0];
  __shared__ float s_eeb[F0];
  __shared__ float s_bk[(F0 + NENV) * F1];          // 768
  __shared__ float s_bb[F1];
  __shared__ float s_is2[NENV];
  __shared__ unsigned short s_ghT[4][D * 8];        // [kslot g][d][8] bf16, no pad
  __shared__ float s_d1k[4 * D];
  __shared__ float s_d1b[D];
  __shared__ unsigned short s_betah[4][4][NB * 8];  // [wave][g][n][8] bf16
  __shared__ float s_inp[4][NB * 8];                // also reused as s_res (wave-local)

  const int tid = threadIdx.x;
  const int w   = tid >> 6;
  const int l   = tid & 63;
  const int be  = blockIdx.x * 4 + w;

  // ---- distributed W -> Wt bf16 conversion over the first 64 blocks ----
  if (blockIdx.x < 64) {
    const int i  = blockIdx.x * 256 + tid;   // [0, 16384)
    const int d  = i >> 6;                   // 0..255
    const int kg = i & 63;                   // 0..63
    ushort4 p;
    p.x = f2bf(out_kernel[(4 * kg + 0) * D + d]);
    p.y = f2bf(out_kernel[(4 * kg + 1) * D + d]);
    p.z = f2bf(out_kernel[(4 * kg + 2) * D + d]);
    p.w = f2bf(out_kernel[(4 * kg + 3) * D + d]);
    *(ushort4*)&wt[d * WT_STRIDE + 4 * kg] = p;
  }

  // ---- staging: small weights ----
  for (int i = tid; i < 888; i += 256) {
    if (i < 64)        s_eek[i]       = ee_kernel[i];
    else if (i < 80)   s_eeb[i - 64]  = ee_bias[i - 64];
    else if (i < 848)  s_bk[i - 80]   = beta_kernel[i - 80];
    else if (i < 880)  s_bb[i - 848]  = beta_bias[i - 848];
    else { float s = ee_scales[i - 880]; s_is2[i - 880] = 1.0f / (s * s); }
  }
  // ---- staging: gamma -> bf16 transposed, k-chunked (thread t owns row d=t) ----
  {
    const int d = tid;
    unsigned int pk[16];
    #pragma unroll
    for (int k2 = 0; k2 < 16; ++k2) {
      unsigned short lo = f2bf(gamma_kernel[(2 * k2 + 0) * D + d]);
      unsigned short hi = f2bf(gamma_kernel[(2 * k2 + 1) * D + d]);
      pk[k2] = (unsigned int)lo | ((unsigned int)hi << 16);
    }
    #pragma unroll
    for (int g = 0; g < 4; ++g)
      *(uint4*)&s_ghT[g][d * 8] = make_uint4(pk[4*g], pk[4*g+1], pk[4*g+2], pk[4*g+3]);
  }
  // ---- staging: dense1 ----
  *(float4*)&s_d1k[4 * tid] = *(const float4*)(dense1_kernel + 4 * tid);
  if (tid < 64) *(float4*)&s_d1b[4 * tid] = *(const float4*)(dense1_bias + 4 * tid);

  __syncthreads();

  // ---- phase 1: pairwise filter -> s_betah[w] (bf16), s_inp[w] ----
  {
    const int n  = l & 31;
    const int cg = l >> 5;
    float rx = r[be * 3 + 0];
    float ry = r[be * 3 + 1];
    float rz = r[be * 3 + 2];
    const float* rn = r_nb + (be * NB + n) * 3;
    float dx = rn[0] - rx;
    float dy = rn[1] - ry;
    float dz = rn[2] - rz;
    float d2 = dx * dx + dy * dy + dz * dz;
    float dist = sqrtf(d2);
    float feats[4] = {dist, dx, dy, dz};
    float h[F0];
    #pragma unroll
    for (int j = 0; j < F0; ++j) {
      float t = s_eeb[j];
      #pragma unroll
      for (int i = 0; i < 4; ++i) t += feats[i] * s_eek[i * F0 + j];
      h[j] = fast_tanh(t);
    }
    float env[NENV];
    #pragma unroll
    for (int s = 0; s < NENV; ++s) env[s] = __expf(-d2 * s_is2[s]);
    float xc = dist * (1.0f / CUT);
    float fcut = (xc < 1.0f)
               ? 0.5f * (__cosf(3.14159265358979323846f * xc) + 1.0f)
               : 0.0f;
    if (cg == 0) {
      float lp = log1pf(dist);
      float inv = lp / dist;
      *(float4*)&s_inp[w][n * 8] = make_float4(lp, dx * inv, dy * inv, dz * inv);
    }
    unsigned int pk[8];
    #pragma unroll
    for (int c4 = 0; c4 < 4; ++c4) {
      float bb[4];
      #pragma unroll
      for (int cc = 0; cc < 4; ++cc) {
        int c = cg * 16 + c4 * 4 + cc;
        float a = s_bb[c];
        #pragma unroll
        for (int k = 0; k < F0; ++k) a += h[k] * s_bk[k * F1 + c];
        #pragma unroll
        for (int s = 0; s < NENV; ++s) a += env[s] * s_bk[(F0 + s) * F1 + c];
        bb[cc] = a * fcut;
      }
      pk[c4 * 2 + 0] = (unsigned int)f2bf(bb[0]) | ((unsigned int)f2bf(bb[1]) << 16);
      pk[c4 * 2 + 1] = (unsigned int)f2bf(bb[2]) | ((unsigned int)f2bf(bb[3]) << 16);
    }
    // k-chunks 2cg and 2cg+1 for row n
    *(uint4*)&s_betah[w][2 * cg + 0][n * 8] = make_uint4(pk[0], pk[1], pk[2], pk[3]);
    *(uint4*)&s_betah[w][2 * cg + 1][n * 8] = make_uint4(pk[4], pk[5], pk[6], pk[7]);
  }
  __syncthreads();

  // ---- phase 2: MFMA gammaM = beta @ G, Hadamard with feat, reduce over n ----
  const int li = l & 15;          // d-within-tile / m-within-tile
  const int g  = l >> 4;          // k-slot group (and C row group)

  // A fragments for the two m-tiles
  s16x8 a0 = *(const s16x8*)&s_betah[w][g][(0 * 16 + li) * 8];
  s16x8 a1 = *(const s16x8*)&s_betah[w][g][(1 * 16 + li) * 8];

  // inp rows this lane will need: nrow = mt*16 + g*4 + reg  (reused all nt)
  float4 ip[8];
  #pragma unroll
  for (int mt = 0; mt < 2; ++mt)
    #pragma unroll
    for (int reg = 0; reg < 4; ++reg)
      ip[mt * 4 + reg] = *(const float4*)&s_inp[w][(mt * 16 + g * 4 + reg) * 8];

  float rpart[16];
  #pragma unroll
  for (int nt = 0; nt < 16; ++nt) {
    const int d = nt * 16 + li;
    s16x8 b = *(const s16x8*)&s_ghT[g][d * 8];
    f32x4 z = {0.f, 0.f, 0.f, 0.f};
    f32x4 c0 = __builtin_amdgcn_mfma_f32_16x16x32_bf16(a0, b, z, 0, 0, 0);
    f32x4 c1 = __builtin_amdgcn_mfma_f32_16x16x32_bf16(a1, b, z, 0, 0, 0);
    float w0 = s_d1k[0 * D + d];
    float w1 = s_d1k[1 * D + d];
    float w2 = s_d1k[2 * D + d];
    float w3 = s_d1k[3 * D + d];
    float bia = s_d1b[d];
    float p = 0.f;
    #pragma unroll
    for (int reg = 0; reg < 4; ++reg) {
      float4 i0 = ip[reg];
      float aa0 = bia + i0.x * w0 + i0.y * w1 + i0.z * w2 + i0.w * w3;
      p += silu(aa0) * c0[reg];
      float4 i1 = ip[4 + reg];
      float aa1 = bia + i1.x * w0 + i1.y * w1 + i1.z * w2 + i1.w * w3;
      p += silu(aa1) * c1[reg];
    }
    rpart[nt] = p;
  }
  #pragma unroll
  for (int nt = 0; nt < 16; ++nt) {
    float v = rpart[nt];
    v += __shfl_xor(v, 16);
    v += __shfl_xor(v, 32);
    rpart[nt] = v;
  }
  // transpose via wave-local LDS (reuse s_inp[w]; ip already consumed)
  float* s_resw = &s_inp[w][0];
  #pragma unroll
  for (int nt = 0; nt < 16; ++nt) {
    if (g == (nt & 3)) s_resw[nt * 16 + li] = rpart[nt];
  }
  float4 rv = *(const float4*)&s_resw[4 * l];
  ushort4 rp;
  rp.x = f2bf(rv.x); rp.y = f2bf(rv.y); rp.z = f2bf(rv.z); rp.w = f2bf(rv.w);
  *(ushort4*)(resh + be * D + 4 * l) = rp;
}

// ---------------------------------------------------------------------------
// Kernel B: out = silu(res @ W + b), bf16 MFMA, LDS-free.
// 512 blocks x 16 rows; wave w handles cols [w*64, w*64+64) (4 n-tiles).
// Fragment recipe identical to the one validated in phase12.
// ---------------------------------------------------------------------------
__global__ __launch_bounds__(256, 4) void moon_outgemm(
    const unsigned short* __restrict__ resh, // [8192,256] bf16
    const unsigned short* __restrict__ wt,   // [256,WT_STRIDE] bf16 (W^T)
    const float* __restrict__ bias,          // [256]
    float* __restrict__ out)                 // [8192,256]
{
  const int tid = threadIdx.x;
  const int w   = tid >> 6;
  const int l   = tid & 63;
  const int li  = l & 15;
  const int g   = l >> 4;
  const int row0 = blockIdx.x * 16;

  float bi[4];
  #pragma unroll
  for (int nt = 0; nt < 4; ++nt) bi[nt] = bias[(w * 4 + nt) * 16 + li];

  f32x4 acc[4] = {{0.f,0.f,0.f,0.f},{0.f,0.f,0.f,0.f},{0.f,0.f,0.f,0.f},{0.f,0.f,0.f,0.f}};
  const unsigned short* ap = resh + (row0 + li) * D + g * 8;
  const unsigned short* bp = wt + (w * 64 + li) * WT_STRIDE + g * 8;

  #pragma unroll
  for (int ks = 0; ks < 8; ++ks) {
    s16x8 a = *(const s16x8*)(ap + ks * 32);
    #pragma unroll
    for (int nt = 0; nt < 4; ++nt) {
      s16x8 b = *(const s16x8*)(bp + nt * 16 * WT_STRIDE + ks * 32);
      acc[nt] = __builtin_amdgcn_mfma_f32_16x16x32_bf16(a, b, acc[nt], 0, 0, 0);
    }
  }
  // C mapping: col(li)=d-within-tile, row=g*4+reg=m-within-tile
  #pragma unroll
  for (int nt = 0; nt < 4; ++nt) {
    #pragma unroll
    for (int reg = 0; reg < 4; ++reg) {
      int row = row0 + g * 4 + reg;
      int col = (w * 4 + nt) * 16 + li;
      out[row * D + col] = silu(acc[nt][reg] + bi[nt]);
    }
  }
}

extern "C" void kernel_launch(void* const* d_in, const int* in_sizes, int n_in,
                              void* d_out, int out_size, void* d_ws, size_t ws_size,
                              hipStream_t stream) {
  const float* r            = (const float*)d_in[0];
  const float* r_nb         = (const float*)d_in[1];
  const float* ee_scales    = (const float*)d_in[2];
  const float* ee_kernel    = (const float*)d_in[3];
  const float* ee_bias      = (const float*)d_in[4];
  const float* beta_kernel  = (const float*)d_in[5];
  const float* beta_bias    = (const float*)d_in[6];
  const float* gamma_kernel = (const float*)d_in[7];
  const float* dense1_kernel= (const float*)d_in[8];
  const float* dense1_bias  = (const float*)d_in[9];
  const float* out_kernel   = (const float*)d_in[10];
  const float* out_bias     = (const float*)d_in[11];
  float* out = (float*)d_out;

  unsigned short* resh = (unsigned short*)d_ws;                       // 4 MB bf16
  unsigned short* wt   = (unsigned short*)((char*)d_ws + 4 * 1024 * 1024); // 132 KB bf16

  hipLaunchKernelGGL(moon_phase12, dim3(PAIRS / 4), dim3(256), 0, stream,
                     r, r_nb, ee_scales, ee_kernel, ee_bias,
                     beta_kernel, beta_bias, gamma_kernel,
                     dense1_kernel, dense1_bias, out_kernel, resh, wt);
  hipLaunchKernelGGL(moon_outgemm, dim3(PAIRS / 16), dim3(256), 0, stream,
                     resh, wt, out_bias, out);
}